// Round 12
// baseline (123.233 us; speedup 1.0000x reference)
//
#include <hip/hip_runtime.h>
#include <hip/hip_bf16.h>
#include <math.h>

#define B_   2
#define N_   512
#define FN   128
#define FE   16
#define MID_ 128

typedef __attribute__((ext_vector_type(8)))  short short8_t;
typedef __attribute__((ext_vector_type(16))) float f32x16;

__device__ __forceinline__ short f2bf(float f) {
    __bf16 h = (__bf16)f;                    // fptrunc -> RNE bf16
    return __builtin_bit_cast(short, h);
}
__device__ __forceinline__ float bf2f(short s) {
    return __uint_as_float(((unsigned)(unsigned short)s) << 16);
}

// ---------------------------------------------------------------------------
// kFull round 12: ONE kernel, 512 blocks x 512 thr (2 blocks/CU), no grid sync.
// Block (b,jt,ic):
//  1. coop msgg (g@Wg + b1+be+bg) + adj ballots
//  2. pre-phase: waves ih=0 -> m2l = feat_i@W2 + b2 (4x8 MFMA);
//                waves ih=1 -> c1l = feat_j@W1 + msgg (4x8 MFMA)   [kA deleted]
//  3. main loop (r10 kB, proven): ef direct global->reg, C-seed from ballots
//  4. merge + epilogue -> partials via agent-scope atomic u32 stores
//  5. cnt[(b,jt)] acq_rel fetch_add; 16th block: max 16 partials ->
//     out = feat_j@Wo1 + msgs(hi+lo bf16)@Wo2 + bo1 + bo2  (24 MFMA)  [kC deleted]
// cnt zeroed per call by captured hipMemsetAsync. Deterministic: max is
// order-independent; last-block math fixed; no spins (no co-residency need).
// ---------------------------------------------------------------------------
__global__ __launch_bounds__(512, 4) void kFull(
    const float* __restrict__ feat, const float* __restrict__ ef,
    const float* __restrict__ gf,   const float* __restrict__ adj,
    const float* __restrict__ W1, const float* __restrict__ b1,
    const float* __restrict__ W2, const float* __restrict__ b2,
    const float* __restrict__ We, const float* __restrict__ be,
    const float* __restrict__ Wg, const float* __restrict__ bg,
    const float* __restrict__ Wo1, const float* __restrict__ bo1,
    const float* __restrict__ Wo2, const float* __restrict__ bo2,
    unsigned* __restrict__ partu, unsigned* __restrict__ cnt,
    float* __restrict__ out)
{
    __shared__ float    c1l[32 * MID_];      // 16 KB  msg1c(+msgg) j-rows
    __shared__ float    m2l[32 * MID_];      // 16 KB  msg2(+b2) i-rows; reused as ftile
    __shared__ float    mtile[32 * 132];     // 16.5 KB merge tile; reused as msl[32][132]
    __shared__ float    msggp[4][MID_];      // 2 KB
    __shared__ unsigned madj[32];
    __shared__ float    anyzf[32];
    __shared__ int      islast;

    const int bid = blockIdx.x;              // 512 = 2b * 16jt * 16ic
    const int b   = bid >> 8;
    const int jt  = (bid >> 4) & 15;
    const int ic  = bid & 15;
    const int j0  = jt * 32, i0 = ic * 32;
    const int t    = threadIdx.x;
    const int lane = t & 63, wid = t >> 6;
    const int mt   = wid & 3, ih = wid >> 2;
    const int g    = lane >> 5, lm = lane & 31;

    // ---- step 1: msgg partials (coop, deterministic tree) + adj ballots ----
    {
        const int col = t & 127, seg = t >> 7;
        const float* gb  = gf + b * FN;
        const float* wgp = Wg + (size_t)(seg * 32) * MID_ + col;
        float p = 0.f;
        #pragma unroll 8
        for (int k = 0; k < 32; ++k) p += gb[seg * 32 + k] * wgp[(size_t)k * MID_];
        msggp[seg][col] = p;
    }
    #pragma unroll
    for (int p = 0; p < 2; ++p) {
        const int i_l = wid * 4 + 2 * p + g;
        const float av = adj[(size_t)(b * N_ + i0 + i_l) * N_ + j0 + lm];
        const unsigned long long bal = __ballot(av != 0.0f);
        if (lane == 0)  madj[wid * 4 + 2 * p]     = (unsigned)bal;
        if (lane == 32) madj[wid * 4 + 2 * p + 1] = (unsigned)(bal >> 32);
    }
    __syncthreads();
    // ---- step 2: msgg reduce + anyzf ----
    if (t < 128) {
        msggp[0][t] = msggp[0][t] + msggp[1][t] + msggp[2][t] + msggp[3][t]
                    + b1[t] + be[t] + bg[t];
    } else if (t < 160) {
        unsigned ao = 0xFFFFFFFFu;
        #pragma unroll
        for (int i2 = 0; i2 < 32; ++i2) ao &= madj[i2];
        const int jl = t - 128;
        anyzf[jl] = ((ao >> jl) & 1u) ? -INFINITY : 0.0f;
    }
    __syncthreads();
    // ---- step 3: pre-phase GEMMs (r10-kA-validated fragment mappings) ----
    {
        const int   c0    = mt * 32;
        const int   rbase = (ih == 0) ? i0 : j0;
        const float* Wm   = (ih == 0) ? W2 : W1;
        short8_t Af[8];
        #pragma unroll
        for (int ks = 0; ks < 8; ++ks) {
            const float* ap = feat + (size_t)(b * N_ + rbase + lm) * FN + ks * 16 + 8 * g;
            const float4 a0 = *(const float4*)ap;
            const float4 a1 = *(const float4*)(ap + 4);
            short8_t A;
            A[0] = f2bf(a0.x); A[1] = f2bf(a0.y); A[2] = f2bf(a0.z); A[3] = f2bf(a0.w);
            A[4] = f2bf(a1.x); A[5] = f2bf(a1.y); A[6] = f2bf(a1.z); A[7] = f2bf(a1.w);
            Af[ks] = A;
        }
        const float initv = (ih == 0) ? b2[c0 + lm] : msggp[0][c0 + lm];
        f32x16 acc;
        #pragma unroll
        for (int r = 0; r < 16; ++r) acc[r] = initv;
        #pragma unroll
        for (int ks = 0; ks < 8; ++ks) {
            short8_t Bv;
            #pragma unroll
            for (int j = 0; j < 8; ++j)
                Bv[j] = f2bf(Wm[(size_t)(ks * 16 + 8 * g + j) * MID_ + c0 + lm]);
            acc = __builtin_amdgcn_mfma_f32_32x32x16_bf16(Af[ks], Bv, acc, 0, 0, 0);
        }
        float* dstl = (ih == 0) ? m2l : c1l;
        #pragma unroll
        for (int r = 0; r < 16; ++r) {
            const int row = (r & 3) + 8 * (r >> 2) + 4 * g;
            dstl[row * MID_ + c0 + lm] = acc[r];
        }
    }
    // We B-fragment for main loop
    short8_t Bf;
    #pragma unroll
    for (int jj = 0; jj < 8; ++jj)
        Bf[jj] = f2bf(We[(8 * g + jj) * MID_ + mt * 32 + lm]);

    f32x16 accm;
    #pragma unroll
    for (int r = 0; r < 16; ++r) accm[r] = -INFINITY;

    __syncthreads();    // m2l, c1l ready

    // ---- step 4: main loop (r10 kB, proven fast) ----
    const float* efr = ef + (((size_t)(b * N_ + i0 + ih * 16)) * N_ + j0 + lm) * FE + 8 * g;
    #pragma unroll 2
    for (int ii = 0; ii < 16; ++ii) {
        const int i_l = ih * 16 + ii;
        const float4 ea = *(const float4*)efr;
        const float4 eb = *(const float4*)(efr + 4);
        efr += (size_t)N_ * FE;
        short8_t Af;
        Af[0] = f2bf(ea.x); Af[1] = f2bf(ea.y); Af[2] = f2bf(ea.z); Af[3] = f2bf(ea.w);
        Af[4] = f2bf(eb.x); Af[5] = f2bf(eb.y); Af[6] = f2bf(eb.z); Af[7] = f2bf(eb.w);

        const unsigned vmg = madj[i_l] >> (4 * g);
        const float m2v = m2l[i_l * MID_ + mt * 32 + lm];      // b2 already folded
        f32x16 C;
        #pragma unroll
        for (int r = 0; r < 16; ++r) {
            const int cr = (r & 3) + 8 * (r >> 2);
            C[r] = (vmg & (1u << cr)) ? m2v : -INFINITY;
        }
        const f32x16 S = __builtin_amdgcn_mfma_f32_32x32x16_bf16(Af, Bf, C, 0, 0, 0);
        #pragma unroll
        for (int r = 0; r < 16; ++r) accm[r] = fmaxf(accm[r], S[r]);
    }

    // ---- merge (pairwise, no atomics) ----
    if (ih == 1) {
        #pragma unroll
        for (int r = 0; r < 16; ++r) {
            const int jrow = (r & 3) + 8 * (r >> 2) + 4 * g;
            mtile[mt * 1056 + jrow * 33 + lm] = accm[r];   // padded sub-tiles, conflict-light
        }
    }
    __syncthreads();
    float* ftile = m2l;    // m2l reads done
    if (ih == 0) {
        #pragma unroll
        for (int r = 0; r < 16; ++r) {
            const int jrow = (r & 3) + 8 * (r >> 2) + 4 * g;
            ftile[jrow * MID_ + mt * 32 + lm] =
                fmaxf(accm[r], mtile[mt * 1056 + jrow * 33 + lm]);
        }
    }
    __syncthreads();

    // ---- epilogue: +c1l, 0-floor, agent-scope partial store ----
    {
        const int jrow = t >> 4, m0 = (t & 15) * 8;
        const float az = anyzf[jrow];
        const float* tl = &ftile[jrow * MID_ + m0];
        const float* c1 = &c1l[jrow * MID_ + m0];
        const size_t pb = ((size_t)(ic * 2 + b) * N_ + j0 + jrow) * MID_ + m0;
        #pragma unroll
        for (int q = 0; q < 8; ++q) {
            const float v = fmaxf(tl[q] + c1[q], az);
            __hip_atomic_store(&partu[pb + q], __float_as_uint(v),
                               __ATOMIC_RELAXED, __HIP_MEMORY_SCOPE_AGENT);
        }
    }
    __syncthreads();   // compiler drains vmcnt before barrier -> stores complete
    if (t == 0)
        islast = (__hip_atomic_fetch_add(&cnt[(b << 4) | jt], 1u,
                    __ATOMIC_ACQ_REL, __HIP_MEMORY_SCOPE_AGENT) == 15u);
    __syncthreads();
    if (!islast) return;

    // ---- step 5 (16th block for (b,jt) only): kC work ----
    float* msl = mtile;                    // [32][132]
    {
        const int jrow = t >> 4, m0 = (t & 15) * 8;
        float v[8];
        #pragma unroll
        for (int q = 0; q < 8; ++q) v[q] = -INFINITY;
        #pragma unroll
        for (int icc = 0; icc < 16; ++icc) {
            const size_t pb = ((size_t)(icc * 2 + b) * N_ + j0 + jrow) * MID_ + m0;
            #pragma unroll
            for (int q = 0; q < 8; ++q) {
                const float pv = __uint_as_float(__hip_atomic_load(&partu[pb + q],
                                    __ATOMIC_RELAXED, __HIP_MEMORY_SCOPE_AGENT));
                v[q] = fmaxf(v[q], pv);
            }
        }
        #pragma unroll
        for (int q = 0; q < 8; ++q) msl[jrow * 132 + m0 + q] = v[q];
    }
    __syncthreads();
    if (ih == 0) {                         // waves 0-3: out col-tiles
        const int c0 = mt * 32;
        const float initv = bo1[c0 + lm] + bo2[c0 + lm];
        f32x16 acc;
        #pragma unroll
        for (int r = 0; r < 16; ++r) acc[r] = initv;
        #pragma unroll
        for (int ks = 0; ks < 8; ++ks) {
            short8_t B2v, B1v;
            #pragma unroll
            for (int j = 0; j < 8; ++j) {
                B2v[j] = f2bf(Wo2[(size_t)(ks * 16 + 8 * g + j) * MID_ + c0 + lm]);
                B1v[j] = f2bf(Wo1[(size_t)(ks * 16 + 8 * g + j) * MID_ + c0 + lm]);
            }
            const float* mp = &msl[lm * 132 + ks * 16 + 8 * g];
            short8_t Mh, Ml;
            #pragma unroll
            for (int q = 0; q < 8; ++q) {
                const float mv = mp[q];
                const short hs = f2bf(mv);
                Mh[q] = hs;
                Ml[q] = f2bf(mv - bf2f(hs));     // hi/lo split: msgs err ~2^-18
            }
            const float* ap = feat + (size_t)(b * N_ + j0 + lm) * FN + ks * 16 + 8 * g;
            const float4 a0 = *(const float4*)ap;
            const float4 a1 = *(const float4*)(ap + 4);
            short8_t Aj;
            Aj[0] = f2bf(a0.x); Aj[1] = f2bf(a0.y); Aj[2] = f2bf(a0.z); Aj[3] = f2bf(a0.w);
            Aj[4] = f2bf(a1.x); Aj[5] = f2bf(a1.y); Aj[6] = f2bf(a1.z); Aj[7] = f2bf(a1.w);

            acc = __builtin_amdgcn_mfma_f32_32x32x16_bf16(Mh, B2v, acc, 0, 0, 0);
            acc = __builtin_amdgcn_mfma_f32_32x32x16_bf16(Ml, B2v, acc, 0, 0, 0);
            acc = __builtin_amdgcn_mfma_f32_32x32x16_bf16(Aj, B1v, acc, 0, 0, 0);
        }
        #pragma unroll
        for (int r = 0; r < 16; ++r) {
            const int row = (r & 3) + 8 * (r >> 2) + 4 * g;
            out[(size_t)(b * N_ + j0 + row) * MID_ + c0 + lm] = acc[r];
        }
    }
}

// ---------------------------------------------------------------------------
extern "C" void kernel_launch(void* const* d_in, const int* in_sizes, int n_in,
                              void* d_out, int out_size, void* d_ws, size_t ws_size,
                              hipStream_t stream)
{
    const float* feat = (const float*)d_in[0];
    const float* ef   = (const float*)d_in[1];
    const float* gf   = (const float*)d_in[2];
    const float* adj  = (const float*)d_in[3];
    const float* W1   = (const float*)d_in[4];
    const float* b1   = (const float*)d_in[5];
    const float* W2   = (const float*)d_in[6];
    const float* b2   = (const float*)d_in[7];
    const float* We   = (const float*)d_in[8];
    const float* be   = (const float*)d_in[9];
    const float* Wg   = (const float*)d_in[10];
    const float* bg   = (const float*)d_in[11];
    const float* Wo1  = (const float*)d_in[12];
    const float* bo1  = (const float*)d_in[13];
    const float* Wo2  = (const float*)d_in[14];
    const float* bo2  = (const float*)d_in[15];
    float* out = (float*)d_out;

    unsigned* partu = (unsigned*)d_ws;                 // 16ic*2b*512*128 u32 = 8 MB
    unsigned* cnt   = partu + 2097152;                 // 32 u32

    hipMemsetAsync(cnt, 0, 32 * sizeof(unsigned), stream);   // capture-legal node
    hipLaunchKernelGGL(kFull, dim3(512), dim3(512), 0, stream,
        feat, ef, gf, adj, W1, b1, W2, b2, We, be, Wg, bg,
        Wo1, bo1, Wo2, bo2, partu, cnt, out);
}

// Round 13
// 75.502 us; speedup vs baseline: 1.6322x; 1.6322x over previous
//
#include <hip/hip_runtime.h>
#include <hip/hip_bf16.h>
#include <math.h>

#define B_   2
#define N_   512
#define FN   128
#define FE   16
#define MID_ 128

typedef __attribute__((ext_vector_type(8)))  short short8_t;
typedef __attribute__((ext_vector_type(16))) float f32x16;

__device__ __forceinline__ short f2bf(float f) {
    __bf16 h = (__bf16)f;                    // fptrunc -> RNE bf16
    return __builtin_bit_cast(short, h);
}
// monotonic f32 -> u32 encode; max in u32 domain == fmax. enc(x) > 0 for all
// finite/inf x  =>  memset-0 is the identity init for atomicMax.
__device__ __forceinline__ unsigned enc_f32(float f) {
    unsigned u = __float_as_uint(f);
    return u ^ (0x80000000u | (unsigned)((int)u >> 31));
}
__device__ __forceinline__ float dec_f32(unsigned u) {
    unsigned m = (u & 0x80000000u) ? 0x80000000u : 0xFFFFFFFFu;
    return __uint_as_float(u ^ m);
}

// ---------------------------------------------------------------------------
// kA: three feat@W GEMMs as one-wave 32x32 MFMA tiles (8 K-steps of 16) +
// msgs_enc zeroing spread across blocks (no extra graph node).
// grid 386 x 64 thr (r10 body + zeroing).
// ---------------------------------------------------------------------------
__global__ __launch_bounds__(64) void kA(
    const float* __restrict__ feat, const float* __restrict__ gfeat,
    const float* __restrict__ W1, const float* __restrict__ b1,
    const float* __restrict__ W2, const float* __restrict__ be,
    const float* __restrict__ Wg, const float* __restrict__ bg,
    const float* __restrict__ Wo1,
    float* __restrict__ msg1c, float* __restrict__ msg2, float* __restrict__ h1,
    float* __restrict__ msgg, unsigned* __restrict__ msgs_enc)
{
    const int bid = blockIdx.x;
    const int t   = threadIdx.x;

    // ---- zero msgs_enc slice (131072 u32 = 32768 uint4 over 386 blocks) ----
    {
        const int s0 = bid * 86;
        #pragma unroll
        for (int q = 0; q < 2; ++q) {
            const int rel = t + 64 * q;
            const int slot = s0 + rel;
            if (rel < 86 && slot < 32768)
                ((uint4*)msgs_enc)[slot] = make_uint4(0u, 0u, 0u, 0u);
        }
    }

    if (bid >= 384) {            // ---- msgg blocks (one per b) ----
        const int b = bid - 384;
        const float* gb = gfeat + b * FN;
        #pragma unroll
        for (int half = 0; half < 2; ++half) {
            const int m = t + 64 * half;
            float mg = b1[m] + be[m] + bg[m];
            for (int k0 = 0; k0 < FN; k0 += 16) {
                float wv[16];
                #pragma unroll
                for (int u = 0; u < 16; ++u) wv[u] = Wg[(k0 + u) * MID_ + m];
                #pragma unroll
                for (int u = 0; u < 16; ++u) mg += gb[k0 + u] * wv[u];
            }
            msgg[b * MID_ + m] = mg;
        }
        return;
    }

    // ---- GEMM tile blocks ----
    const int bb  = bid / 192;               // batch
    const int rem = bid - bb * 192;
    const int nt  = rem / 12;                // row tile (32 rows)
    const int ct  = rem - nt * 12;           // 0..11
    const int w   = ct >> 2;                 // which W
    const int c0  = (ct & 3) * 32;           // col base
    const int n0  = nt * 32;
    const int g   = t >> 5, lm = t & 31;

    const float* Ws  = (w == 0) ? W1    : (w == 1) ? W2   : Wo1;
    float*       dst = (w == 0) ? msg1c : (w == 1) ? msg2 : h1;

    short8_t Af[8];
    #pragma unroll
    for (int ks = 0; ks < 8; ++ks) {
        const float* ap = feat + (size_t)(bb * N_ + n0 + lm) * FN + ks * 16 + 8 * g;
        const float4 a0 = *(const float4*)ap;
        const float4 a1 = *(const float4*)(ap + 4);
        short8_t A;
        A[0] = f2bf(a0.x); A[1] = f2bf(a0.y); A[2] = f2bf(a0.z); A[3] = f2bf(a0.w);
        A[4] = f2bf(a1.x); A[5] = f2bf(a1.y); A[6] = f2bf(a1.z); A[7] = f2bf(a1.w);
        Af[ks] = A;
    }
    short8_t Bfr[8];
    #pragma unroll
    for (int ks = 0; ks < 8; ++ks) {
        short8_t Bv;
        #pragma unroll
        for (int j = 0; j < 8; ++j)
            Bv[j] = f2bf(Ws[(size_t)(ks * 16 + 8 * g + j) * MID_ + c0 + lm]);
        Bfr[ks] = Bv;
    }

    f32x16 acc;
    #pragma unroll
    for (int r = 0; r < 16; ++r) acc[r] = 0.0f;
    #pragma unroll
    for (int ks = 0; ks < 8; ++ks)
        acc = __builtin_amdgcn_mfma_f32_32x32x16_bf16(Af[ks], Bfr[ks], acc, 0, 0, 0);

    #pragma unroll
    for (int r = 0; r < 16; ++r) {
        const int row = (r & 3) + 8 * (r >> 2) + 4 * g;
        dst[(size_t)(bb * N_ + n0 + row) * MID_ + c0 + lm] = acc[r];
    }
}

// ---------------------------------------------------------------------------
// kB round 13: r10 body + (a) explicit 1-deep ef prefetch in a fully
// unrolled main loop (loads for i+1 issue before MFMA of i), (b) epilogue
// does 8 global atomicMax on enc-u32 msgs (kills the 16 MB part round-trip).
// grid 512 = 2b x 16jt x 16ic; block 512 = 8 waves = 4mt x 2ih.
// ---------------------------------------------------------------------------
__global__ __launch_bounds__(512, 4) void kB(
    const float* __restrict__ ef, const float* __restrict__ adj,
    const float* __restrict__ We, const float* __restrict__ b2,
    const float* __restrict__ msg1c, const float* __restrict__ msg2,
    const float* __restrict__ msgg,
    unsigned* __restrict__ msgs_enc)
{
    __shared__ float    m2l[32 * MID_];    // 16 KB; reused as final tile after merge
    __shared__ float    mtile[4][32 * 32]; // 16 KB ih=1 partials
    __shared__ unsigned madj[32];
    __shared__ float    anyzf[32];

    const int bid = blockIdx.x;            // 512 = 2b * 16jt * 16ic
    const int b   = bid >> 8;
    const int jt  = (bid >> 4) & 15;
    const int ic  = bid & 15;
    const int j0  = jt * 32, i0 = ic * 32;
    const int t    = threadIdx.x;
    const int lane = t & 63, wid = t >> 6;
    const int mt   = wid & 3, ih = wid >> 2;
    const int g    = lane >> 5, lm = lane & 31;

    // stage msg2 chunk [32 i][128 m] (coalesced)
    {
        const float4* src = (const float4*)(msg2 + (size_t)(b * N_ + i0) * MID_);
        ((float4*)m2l)[t]       = src[t];
        ((float4*)m2l)[t + 512] = src[t + 512];
    }
    // adj -> bitmasks via ballot (wave covers 4 i via 2 ballots)
    #pragma unroll
    for (int p = 0; p < 2; ++p) {
        const int i_l = wid * 4 + 2 * p + g;
        const float av = adj[(size_t)(b * N_ + i0 + i_l) * N_ + j0 + lm];
        const unsigned long long bal = __ballot(av != 0.0f);
        if (lane == 0)  madj[wid * 4 + 2 * p]     = (unsigned)bal;
        if (lane == 32) madj[wid * 4 + 2 * p + 1] = (unsigned)(bal >> 32);
    }
    // B fragment for this wave's mt: We[k=8g+jj, mt*32+lm]
    short8_t Bf;
    #pragma unroll
    for (int jj = 0; jj < 8; ++jj)
        Bf[jj] = f2bf(We[(8 * g + jj) * MID_ + mt * 32 + lm]);
    const float b2v = b2[mt * 32 + lm];    // msg2 is raw

    f32x16 accm;
    #pragma unroll
    for (int r = 0; r < 16; ++r) accm[r] = -INFINITY;

    __syncthreads();

    if (t < 32) {   // all-ones column -> -inf floor, else 0 (read in epilogue)
        unsigned ao = 0xFFFFFFFFu;
        #pragma unroll
        for (int i2 = 0; i2 < 32; ++i2) ao &= madj[i2];
        anyzf[t] = ((ao >> t) & 1u) ? -INFINITY : 0.0f;
    }

    // ---- main loop: 16 i's, one mt; explicit 1-deep prefetch, full unroll ----
    const float* efr = ef + (((size_t)(b * N_ + i0 + ih * 16)) * N_ + j0 + lm) * FE + 8 * g;
    float4 ea = *(const float4*)efr;
    float4 eb = *(const float4*)(efr + 4);
    efr += (size_t)N_ * FE;
    #pragma unroll
    for (int ii = 0; ii < 16; ++ii) {
        float4 na, nb;
        if (ii < 15) {
            na = *(const float4*)efr;
            nb = *(const float4*)(efr + 4);
            efr += (size_t)N_ * FE;
        }
        const int i_l = ih * 16 + ii;
        short8_t Af;
        Af[0] = f2bf(ea.x); Af[1] = f2bf(ea.y); Af[2] = f2bf(ea.z); Af[3] = f2bf(ea.w);
        Af[4] = f2bf(eb.x); Af[5] = f2bf(eb.y); Af[6] = f2bf(eb.z); Af[7] = f2bf(eb.w);

        const unsigned vmg = madj[i_l] >> (4 * g);
        const float m2v = m2l[i_l * MID_ + mt * 32 + lm] + b2v;
        f32x16 C;
        #pragma unroll
        for (int r = 0; r < 16; ++r) {
            const int cr = (r & 3) + 8 * (r >> 2);
            C[r] = (vmg & (1u << cr)) ? m2v : -INFINITY;
        }
        const f32x16 S = __builtin_amdgcn_mfma_f32_32x32x16_bf16(Af, Bf, C, 0, 0, 0);
        #pragma unroll
        for (int r = 0; r < 16; ++r) accm[r] = fmaxf(accm[r], S[r]);
        ea = na; eb = nb;
    }

    // pairwise cross-wave merge (no atomics)
    if (ih == 1) {
        #pragma unroll
        for (int r = 0; r < 16; ++r) {
            const int jrow = (r & 3) + 8 * (r >> 2) + 4 * g;
            mtile[mt][jrow * 32 + lm] = accm[r];
        }
    }
    __syncthreads();   // mtile ready; all m2l reads done -> safe to reuse as ftile
    float* ftile = m2l;
    if (ih == 0) {
        #pragma unroll
        for (int r = 0; r < 16; ++r) {
            const int jrow = (r & 3) + 8 * (r >> 2) + 4 * g;
            ftile[jrow * MID_ + mt * 32 + lm] = fmaxf(accm[r], mtile[mt][jrow * 32 + lm]);
        }
    }
    __syncthreads();

    // epilogue: + (msg1c_raw + msgg), 0-floor, enc + global atomicMax
    {
        const int jrow = t >> 4, m0 = (t & 15) * 8;
        const float az = anyzf[jrow];
        const float*  c1 = msg1c + (size_t)(b * N_ + j0 + jrow) * MID_ + m0;
        const float*  gg = msgg + b * MID_ + m0;
        const float*  tl = &ftile[jrow * MID_ + m0];
        unsigned* dst = msgs_enc + (size_t)(b * N_ + j0 + jrow) * MID_ + m0;
        #pragma unroll
        for (int q = 0; q < 8; ++q) {
            const float v = fmaxf(tl[q] + c1[q] + gg[q], az);
            atomicMax(dst + q, enc_f32(v));
        }
    }
}

// ---------------------------------------------------------------------------
// kC: msgs = dec(msgs_enc); out = (h1_raw + bo1) + msgs@Wo2 + bo2
// grid 512 = 2b x 256jt (2 rows); block 256 (r10 body minus partial loop)
// ---------------------------------------------------------------------------
__global__ __launch_bounds__(256, 2) void kC(
    const unsigned* __restrict__ msgs_enc, const float* __restrict__ h1,
    const float* __restrict__ Wo2, const float* __restrict__ bo1,
    const float* __restrict__ bo2,
    float* __restrict__ out)
{
    __shared__ float ms[2 * MID_];
    const int bid = blockIdx.x;          // 512 = 2b * 256 tiles
    const int b   = bid >> 8;
    const int j0  = (bid & 255) * 2;
    const int t   = threadIdx.x;
    const int r   = t >> 7, m = t & 127;
    const size_t base = ((size_t)b * N_ + j0 + r) * MID_ + m;

    ms[r * MID_ + m] = dec_f32(msgs_enc[base]);
    __syncthreads();

    float acc = h1[base] + bo1[m] + bo2[m];
    for (int k0 = 0; k0 < MID_; k0 += 8) {
        float wv[8];
        #pragma unroll
        for (int uu = 0; uu < 8; ++uu) wv[uu] = Wo2[(k0 + uu) * MID_ + m];
        #pragma unroll
        for (int uu = 0; uu < 8; ++uu) acc += ms[r * MID_ + k0 + uu] * wv[uu];
    }
    out[base] = acc;
}

// ---------------------------------------------------------------------------
extern "C" void kernel_launch(void* const* d_in, const int* in_sizes, int n_in,
                              void* d_out, int out_size, void* d_ws, size_t ws_size,
                              hipStream_t stream)
{
    const float* feat = (const float*)d_in[0];
    const float* ef   = (const float*)d_in[1];
    const float* gf   = (const float*)d_in[2];
    const float* adj  = (const float*)d_in[3];
    const float* W1   = (const float*)d_in[4];
    const float* b1   = (const float*)d_in[5];
    const float* W2   = (const float*)d_in[6];
    const float* b2   = (const float*)d_in[7];
    const float* We   = (const float*)d_in[8];
    const float* be   = (const float*)d_in[9];
    const float* Wg   = (const float*)d_in[10];
    const float* bg   = (const float*)d_in[11];
    const float* Wo1  = (const float*)d_in[12];
    const float* bo1  = (const float*)d_in[13];
    const float* Wo2  = (const float*)d_in[14];
    const float* bo2  = (const float*)d_in[15];
    float* out = (float*)d_out;

    float*    ws       = (float*)d_ws;
    float*    msg1c    = ws;                          // 131072 f32 (raw feat@W1)
    float*    msg2     = ws + 131072;                 // 131072 f32 (raw feat@W2)
    float*    h1       = ws + 262144;                 // 131072 f32 (raw feat@Wo1)
    unsigned* msgs_enc = (unsigned*)(ws + 393216);    // 131072 u32 (enc msgs)
    float*    msgg     = ws + 393216 + 131072;        // 256 f32

    hipLaunchKernelGGL(kA, dim3(386), dim3(64), 0, stream,
        feat, gf, W1, b1, W2, be, Wg, bg, Wo1, msg1c, msg2, h1, msgg, msgs_enc);
    hipLaunchKernelGGL(kB, dim3(512), dim3(512), 0, stream,
        ef, adj, We, b2, msg1c, msg2, msgg, msgs_enc);
    hipLaunchKernelGGL(kC, dim3(512), dim3(256), 0, stream,
        msgs_enc, h1, Wo2, bo1, bo2, out);
}

// Round 14
// 30.415 us; speedup vs baseline: 4.0516x; 2.4824x over previous
//
#include <hip/hip_runtime.h>
#include <hip/hip_bf16.h>
#include <math.h>

#define B_   2
#define N_   512
#define FN   128
#define FE   16
#define MID_ 128

typedef __attribute__((ext_vector_type(8)))  short short8_t;
typedef __attribute__((ext_vector_type(16))) float f32x16;

__device__ __forceinline__ short f2bf(float f) {
    __bf16 h = (__bf16)f;                    // fptrunc -> RNE bf16
    return __builtin_bit_cast(short, h);
}

// ---------------------------------------------------------------------------
// kA: three feat@W GEMMs as one-wave 32x32 MFMA tiles (8 K-steps of 16).
// grid 386 x 64 thr (byte-identical to round 10 — validated champion).
// ---------------------------------------------------------------------------
__global__ __launch_bounds__(64) void kA(
    const float* __restrict__ feat, const float* __restrict__ gfeat,
    const float* __restrict__ W1, const float* __restrict__ b1,
    const float* __restrict__ W2, const float* __restrict__ be,
    const float* __restrict__ Wg, const float* __restrict__ bg,
    const float* __restrict__ Wo1,
    float* __restrict__ msg1c, float* __restrict__ msg2, float* __restrict__ h1,
    float* __restrict__ msgg)
{
    const int bid = blockIdx.x;
    const int t   = threadIdx.x;

    if (bid >= 384) {            // ---- msgg blocks (one per b) ----
        const int b = bid - 384;
        const float* gb = gfeat + b * FN;
        #pragma unroll
        for (int half = 0; half < 2; ++half) {
            const int m = t + 64 * half;
            float mg = b1[m] + be[m] + bg[m];
            for (int k0 = 0; k0 < FN; k0 += 16) {
                float wv[16];
                #pragma unroll
                for (int u = 0; u < 16; ++u) wv[u] = Wg[(k0 + u) * MID_ + m];
                #pragma unroll
                for (int u = 0; u < 16; ++u) mg += gb[k0 + u] * wv[u];
            }
            msgg[b * MID_ + m] = mg;
        }
        return;
    }

    // ---- GEMM tile blocks ----
    const int bb  = bid / 192;               // batch
    const int rem = bid - bb * 192;
    const int nt  = rem / 12;                // row tile (32 rows)
    const int ct  = rem - nt * 12;           // 0..11
    const int w   = ct >> 2;                 // which W
    const int c0  = (ct & 3) * 32;           // col base
    const int n0  = nt * 32;
    const int g   = t >> 5, lm = t & 31;

    const float* Ws  = (w == 0) ? W1    : (w == 1) ? W2   : Wo1;
    float*       dst = (w == 0) ? msg1c : (w == 1) ? msg2 : h1;

    short8_t Af[8];
    #pragma unroll
    for (int ks = 0; ks < 8; ++ks) {
        const float* ap = feat + (size_t)(bb * N_ + n0 + lm) * FN + ks * 16 + 8 * g;
        const float4 a0 = *(const float4*)ap;
        const float4 a1 = *(const float4*)(ap + 4);
        short8_t A;
        A[0] = f2bf(a0.x); A[1] = f2bf(a0.y); A[2] = f2bf(a0.z); A[3] = f2bf(a0.w);
        A[4] = f2bf(a1.x); A[5] = f2bf(a1.y); A[6] = f2bf(a1.z); A[7] = f2bf(a1.w);
        Af[ks] = A;
    }
    short8_t Bfr[8];
    #pragma unroll
    for (int ks = 0; ks < 8; ++ks) {
        short8_t Bv;
        #pragma unroll
        for (int j = 0; j < 8; ++j)
            Bv[j] = f2bf(Ws[(size_t)(ks * 16 + 8 * g + j) * MID_ + c0 + lm]);
        Bfr[ks] = Bv;
    }

    f32x16 acc;
    #pragma unroll
    for (int r = 0; r < 16; ++r) acc[r] = 0.0f;
    #pragma unroll
    for (int ks = 0; ks < 8; ++ks)
        acc = __builtin_amdgcn_mfma_f32_32x32x16_bf16(Af[ks], Bfr[ks], acc, 0, 0, 0);

    #pragma unroll
    for (int r = 0; r < 16; ++r) {
        const int row = (r & 3) + 8 * (r >> 2) + 4 * g;
        dst[(size_t)(bb * N_ + n0 + row) * MID_ + c0 + lm] = acc[r];
    }
}

// ---------------------------------------------------------------------------
// kB round 14: r10 body, ONE change — main loop batches 4 i-rows: issue 8
// independent float4 loads, then 4x (cvt + C-build + MFMA + fmax).
// (r13 lesson: hand 1-deep prefetch throttled MLP to 263 GB/s = 75 us;
//  compiler unroll-2 gave ~25 us; this guarantees 8 loads in flight.)
// All array indices compile-time after unroll; peak ~95 VGPR < 128 cap.
// grid 512 = 2b x 16jt x 16ic; block 512 = 8 waves = 4mt x 2ih.
// ---------------------------------------------------------------------------
__global__ __launch_bounds__(512, 4) void kB(
    const float* __restrict__ ef, const float* __restrict__ adj,
    const float* __restrict__ We, const float* __restrict__ b2,
    const float* __restrict__ msg1c, const float* __restrict__ msg2,
    const float* __restrict__ msgg,
    float* __restrict__ part)
{
    __shared__ float    m2l[32 * MID_];    // 16 KB; reused as final tile after merge
    __shared__ float    mtile[4][32 * 32]; // 16 KB ih=1 partials
    __shared__ unsigned madj[32];
    __shared__ float    anyzf[32];

    const int bid = blockIdx.x;            // 512 = 2b * 16jt * 16ic
    const int b   = bid >> 8;
    const int jt  = (bid >> 4) & 15;
    const int ic  = bid & 15;
    const int j0  = jt * 32, i0 = ic * 32;
    const int t    = threadIdx.x;
    const int lane = t & 63, wid = t >> 6;
    const int mt   = wid & 3, ih = wid >> 2;
    const int g    = lane >> 5, lm = lane & 31;

    // stage msg2 chunk [32 i][128 m] (coalesced)
    {
        const float4* src = (const float4*)(msg2 + (size_t)(b * N_ + i0) * MID_);
        ((float4*)m2l)[t]       = src[t];
        ((float4*)m2l)[t + 512] = src[t + 512];
    }
    // adj -> bitmasks via ballot (wave covers 4 i via 2 ballots)
    #pragma unroll
    for (int p = 0; p < 2; ++p) {
        const int i_l = wid * 4 + 2 * p + g;
        const float av = adj[(size_t)(b * N_ + i0 + i_l) * N_ + j0 + lm];
        const unsigned long long bal = __ballot(av != 0.0f);
        if (lane == 0)  madj[wid * 4 + 2 * p]     = (unsigned)bal;
        if (lane == 32) madj[wid * 4 + 2 * p + 1] = (unsigned)(bal >> 32);
    }
    // B fragment for this wave's mt: We[k=8g+jj, mt*32+lm]
    short8_t Bf;
    #pragma unroll
    for (int jj = 0; jj < 8; ++jj)
        Bf[jj] = f2bf(We[(8 * g + jj) * MID_ + mt * 32 + lm]);
    const float b2v = b2[mt * 32 + lm];    // msg2 is raw

    f32x16 accm;
    #pragma unroll
    for (int r = 0; r < 16; ++r) accm[r] = -INFINITY;

    __syncthreads();

    if (t < 32) {   // all-ones column -> -inf floor, else 0 (read in epilogue)
        unsigned ao = 0xFFFFFFFFu;
        #pragma unroll
        for (int i2 = 0; i2 < 32; ++i2) ao &= madj[i2];
        anyzf[t] = ((ao >> t) & 1u) ? -INFINITY : 0.0f;
    }

    // ---- main loop: 16 i's as 4 batches of 4 (8 loads in flight/batch) ----
    const float*  efr     = ef + (((size_t)(b * N_ + i0 + ih * 16)) * N_ + j0 + lm) * FE + 8 * g;
    const size_t  rowstep = (size_t)N_ * FE;
    #pragma unroll
    for (int bq = 0; bq < 4; ++bq) {
        float4 la[4], lb[4];
        #pragma unroll
        for (int q = 0; q < 4; ++q) {
            la[q] = *(const float4*)(efr + (size_t)q * rowstep);
            lb[q] = *(const float4*)(efr + (size_t)q * rowstep + 4);
        }
        efr += 4 * rowstep;
        #pragma unroll
        for (int q = 0; q < 4; ++q) {
            const int i_l = ih * 16 + bq * 4 + q;
            short8_t Af;
            Af[0] = f2bf(la[q].x); Af[1] = f2bf(la[q].y);
            Af[2] = f2bf(la[q].z); Af[3] = f2bf(la[q].w);
            Af[4] = f2bf(lb[q].x); Af[5] = f2bf(lb[q].y);
            Af[6] = f2bf(lb[q].z); Af[7] = f2bf(lb[q].w);

            const unsigned vmg = madj[i_l] >> (4 * g);
            const float m2v = m2l[i_l * MID_ + mt * 32 + lm] + b2v;
            f32x16 C;
            #pragma unroll
            for (int r = 0; r < 16; ++r) {
                const int cr = (r & 3) + 8 * (r >> 2);
                C[r] = (vmg & (1u << cr)) ? m2v : -INFINITY;
            }
            const f32x16 S = __builtin_amdgcn_mfma_f32_32x32x16_bf16(Af, Bf, C, 0, 0, 0);
            #pragma unroll
            for (int r = 0; r < 16; ++r) accm[r] = fmaxf(accm[r], S[r]);
        }
    }

    // pairwise cross-wave merge (no atomics)
    if (ih == 1) {
        #pragma unroll
        for (int r = 0; r < 16; ++r) {
            const int jrow = (r & 3) + 8 * (r >> 2) + 4 * g;
            mtile[mt][jrow * 32 + lm] = accm[r];
        }
    }
    __syncthreads();   // mtile ready; all m2l reads done -> safe to reuse as ftile
    float* ftile = m2l;
    if (ih == 0) {
        #pragma unroll
        for (int r = 0; r < 16; ++r) {
            const int jrow = (r & 3) + 8 * (r >> 2) + 4 * g;
            ftile[jrow * MID_ + mt * 32 + lm] = fmaxf(accm[r], mtile[mt][jrow * 32 + lm]);
        }
    }
    __syncthreads();

    // epilogue: + (msg1c_raw + msgg), 0-floor, coalesced f32 store
    {
        const int jrow = t >> 4, m0 = (t & 15) * 8;
        const float az = anyzf[jrow];
        const float*  c1  = msg1c + (size_t)(b * N_ + j0 + jrow) * MID_ + m0;
        const float*  gg  = msgg + b * MID_ + m0;
        float*        dst = part  + ((size_t)(ic * 2 + b) * N_ + j0 + jrow) * MID_ + m0;
        const float*  tl  = &ftile[jrow * MID_ + m0];
        const float4 c1a = *(const float4*)c1;
        const float4 c1b = *(const float4*)(c1 + 4);
        const float4 g1a = *(const float4*)gg;
        const float4 g1b = *(const float4*)(gg + 4);
        float4 o0, o1;
        o0.x = fmaxf(tl[0] + c1a.x + g1a.x, az);
        o0.y = fmaxf(tl[1] + c1a.y + g1a.y, az);
        o0.z = fmaxf(tl[2] + c1a.z + g1a.z, az);
        o0.w = fmaxf(tl[3] + c1a.w + g1a.w, az);
        o1.x = fmaxf(tl[4] + c1b.x + g1b.x, az);
        o1.y = fmaxf(tl[5] + c1b.y + g1b.y, az);
        o1.z = fmaxf(tl[6] + c1b.z + g1b.z, az);
        o1.w = fmaxf(tl[7] + c1b.w + g1b.w, az);
        *(float4*)dst       = o0;
        *(float4*)(dst + 4) = o1;
    }
}

// ---------------------------------------------------------------------------
// kC: msgs = max over 16 f32 partials; out = (h1_raw + bo1) + msgs@Wo2 + bo2
// grid 512 = 2b x 256jt (2 rows); block 256 (byte-identical to round 10)
// ---------------------------------------------------------------------------
__global__ __launch_bounds__(256, 2) void kC(
    const float* __restrict__ part, const float* __restrict__ h1,
    const float* __restrict__ Wo2, const float* __restrict__ bo1,
    const float* __restrict__ bo2,
    float* __restrict__ out)
{
    __shared__ float ms[2 * MID_];
    const int bid = blockIdx.x;          // 512 = 2b * 256 tiles
    const int b   = bid >> 8;
    const int j0  = (bid & 255) * 2;
    const int t   = threadIdx.x;
    const int r   = t >> 7, m = t & 127;
    const size_t base = ((size_t)b * N_ + j0 + r) * MID_ + m;

    float u = -INFINITY;
    #pragma unroll
    for (int icc = 0; icc < 16; ++icc)
        u = fmaxf(u, part[(size_t)icc * 2 * N_ * MID_ + base]);
    ms[r * MID_ + m] = u;
    __syncthreads();

    float acc = h1[base] + bo1[m] + bo2[m];
    for (int k0 = 0; k0 < MID_; k0 += 8) {
        float wv[8];
        #pragma unroll
        for (int uu = 0; uu < 8; ++uu) wv[uu] = Wo2[(k0 + uu) * MID_ + m];
        #pragma unroll
        for (int uu = 0; uu < 8; ++uu) acc += ms[r * MID_ + k0 + uu] * wv[uu];
    }
    out[base] = acc;
}

// ---------------------------------------------------------------------------
extern "C" void kernel_launch(void* const* d_in, const int* in_sizes, int n_in,
                              void* d_out, int out_size, void* d_ws, size_t ws_size,
                              hipStream_t stream)
{
    const float* feat = (const float*)d_in[0];
    const float* ef   = (const float*)d_in[1];
    const float* gf   = (const float*)d_in[2];
    const float* adj  = (const float*)d_in[3];
    const float* W1   = (const float*)d_in[4];
    const float* b1   = (const float*)d_in[5];
    const float* W2   = (const float*)d_in[6];
    const float* b2   = (const float*)d_in[7];
    const float* We   = (const float*)d_in[8];
    const float* be   = (const float*)d_in[9];
    const float* Wg   = (const float*)d_in[10];
    const float* bg   = (const float*)d_in[11];
    const float* Wo1  = (const float*)d_in[12];
    const float* bo1  = (const float*)d_in[13];
    const float* Wo2  = (const float*)d_in[14];
    const float* bo2  = (const float*)d_in[15];
    float* out = (float*)d_out;

    float* ws    = (float*)d_ws;
    float* msg1c = ws;                        // 131072 f32 (raw feat@W1)
    float* msg2  = ws + 131072;               // 131072 f32 (raw feat@W2)
    float* h1    = ws + 262144;               // 131072 f32 (raw feat@Wo1)
    float* part  = ws + 393216;               // 16ic*2b*512*128 f32 = 8 MB
    float* msgg  = ws + 393216 + 2097152;     // 256 f32

    hipLaunchKernelGGL(kA, dim3(386), dim3(64), 0, stream,
        feat, gf, W1, b1, W2, be, Wg, bg, Wo1, msg1c, msg2, h1, msgg);
    hipLaunchKernelGGL(kB, dim3(512), dim3(512), 0, stream,
        ef, adj, We, b2, msg1c, msg2, msgg, part);
    hipLaunchKernelGGL(kC, dim3(512), dim3(256), 0, stream,
        part, h1, Wo2, bo1, bo2, out);
}

// Round 15
// 30.148 us; speedup vs baseline: 4.0875x; 1.0089x over previous
//
#include <hip/hip_runtime.h>
#include <hip/hip_bf16.h>
#include <math.h>

#define B_   2
#define N_   512
#define FN   128
#define FE   16
#define MID_ 128

typedef __attribute__((ext_vector_type(8)))  short short8_t;
typedef __attribute__((ext_vector_type(16))) float f32x16;

__device__ __forceinline__ short f2bf(float f) {
    __bf16 h = (__bf16)f;                    // fptrunc -> RNE bf16
    return __builtin_bit_cast(short, h);
}

// ---------------------------------------------------------------------------
// kA: three feat@W GEMMs as one-wave 32x32 MFMA tiles (8 K-steps of 16).
// grid 386 x 64 thr (byte-identical to round 10 — validated champion).
// ---------------------------------------------------------------------------
__global__ __launch_bounds__(64) void kA(
    const float* __restrict__ feat, const float* __restrict__ gfeat,
    const float* __restrict__ W1, const float* __restrict__ b1,
    const float* __restrict__ W2, const float* __restrict__ be,
    const float* __restrict__ Wg, const float* __restrict__ bg,
    const float* __restrict__ Wo1,
    float* __restrict__ msg1c, float* __restrict__ msg2, float* __restrict__ h1,
    float* __restrict__ msgg)
{
    const int bid = blockIdx.x;
    const int t   = threadIdx.x;

    if (bid >= 384) {            // ---- msgg blocks (one per b) ----
        const int b = bid - 384;
        const float* gb = gfeat + b * FN;
        #pragma unroll
        for (int half = 0; half < 2; ++half) {
            const int m = t + 64 * half;
            float mg = b1[m] + be[m] + bg[m];
            for (int k0 = 0; k0 < FN; k0 += 16) {
                float wv[16];
                #pragma unroll
                for (int u = 0; u < 16; ++u) wv[u] = Wg[(k0 + u) * MID_ + m];
                #pragma unroll
                for (int u = 0; u < 16; ++u) mg += gb[k0 + u] * wv[u];
            }
            msgg[b * MID_ + m] = mg;
        }
        return;
    }

    // ---- GEMM tile blocks ----
    const int bb  = bid / 192;               // batch
    const int rem = bid - bb * 192;
    const int nt  = rem / 12;                // row tile (32 rows)
    const int ct  = rem - nt * 12;           // 0..11
    const int w   = ct >> 2;                 // which W
    const int c0  = (ct & 3) * 32;           // col base
    const int n0  = nt * 32;
    const int g   = t >> 5, lm = t & 31;

    const float* Ws  = (w == 0) ? W1    : (w == 1) ? W2   : Wo1;
    float*       dst = (w == 0) ? msg1c : (w == 1) ? msg2 : h1;

    short8_t Af[8];
    #pragma unroll
    for (int ks = 0; ks < 8; ++ks) {
        const float* ap = feat + (size_t)(bb * N_ + n0 + lm) * FN + ks * 16 + 8 * g;
        const float4 a0 = *(const float4*)ap;
        const float4 a1 = *(const float4*)(ap + 4);
        short8_t A;
        A[0] = f2bf(a0.x); A[1] = f2bf(a0.y); A[2] = f2bf(a0.z); A[3] = f2bf(a0.w);
        A[4] = f2bf(a1.x); A[5] = f2bf(a1.y); A[6] = f2bf(a1.z); A[7] = f2bf(a1.w);
        Af[ks] = A;
    }
    short8_t Bfr[8];
    #pragma unroll
    for (int ks = 0; ks < 8; ++ks) {
        short8_t Bv;
        #pragma unroll
        for (int j = 0; j < 8; ++j)
            Bv[j] = f2bf(Ws[(size_t)(ks * 16 + 8 * g + j) * MID_ + c0 + lm]);
        Bfr[ks] = Bv;
    }

    f32x16 acc;
    #pragma unroll
    for (int r = 0; r < 16; ++r) acc[r] = 0.0f;
    #pragma unroll
    for (int ks = 0; ks < 8; ++ks)
        acc = __builtin_amdgcn_mfma_f32_32x32x16_bf16(Af[ks], Bfr[ks], acc, 0, 0, 0);

    #pragma unroll
    for (int r = 0; r < 16; ++r) {
        const int row = (r & 3) + 8 * (r >> 2) + 4 * g;
        dst[(size_t)(bb * N_ + n0 + row) * MID_ + c0 + lm] = acc[r];
    }
}

// ---------------------------------------------------------------------------
// kB round 15: wave re-partition 4mt x 2ih -> 2mtg x 4ig.
// Each wave: 8 i's, TWO mt tiles per ef fragment (1 load+cvt feeds 2 MFMAs);
// shared msk[r] in {0,-inf} built once, applied by v_add to both C-seeds
// (exact: m2v+0 / m2v+(-inf) == r10's cndmask). Per-output VALU ~131->~81;
// ef load instrs halved. Merge: pairwise LDS tree per mtg (no atomics), then
// r10's coalesced epilogue. VGPR ~100 < 128 cap -> no spill (r6 lesson).
// grid 512 = 2b x 16jt x 16ic; block 512 = 8 waves.
// ---------------------------------------------------------------------------
__global__ __launch_bounds__(512, 4) void kB(
    const float* __restrict__ ef, const float* __restrict__ adj,
    const float* __restrict__ We, const float* __restrict__ b2,
    const float* __restrict__ msg1c, const float* __restrict__ msg2,
    const float* __restrict__ msgg,
    float* __restrict__ part)
{
    __shared__ float    m2l[32 * MID_];      // 16 KB; reused as ftile after merge
    __shared__ float    T[2][2][32 * 64];    // 32 KB merge buffers
    __shared__ unsigned madj[32];
    __shared__ float    anyzf[32];

    const int bid = blockIdx.x;            // 512 = 2b * 16jt * 16ic
    const int b   = bid >> 8;
    const int jt  = (bid >> 4) & 15;
    const int ic  = bid & 15;
    const int j0  = jt * 32, i0 = ic * 32;
    const int t    = threadIdx.x;
    const int lane = t & 63, wid = t >> 6;
    const int mtg  = wid >> 2;             // 0..1: m-half (64 m)
    const int ig   = wid & 3;              // 0..3: i-chunk (8 i)
    const int g    = lane >> 5, lm = lane & 31;

    // stage msg2 chunk [32 i][128 m] (coalesced)
    {
        const float4* src = (const float4*)(msg2 + (size_t)(b * N_ + i0) * MID_);
        ((float4*)m2l)[t]       = src[t];
        ((float4*)m2l)[t + 512] = src[t + 512];
    }
    // adj -> bitmasks via ballot (wave covers 4 i via 2 ballots)
    #pragma unroll
    for (int p = 0; p < 2; ++p) {
        const int i_l = wid * 4 + 2 * p + g;
        const float av = adj[(size_t)(b * N_ + i0 + i_l) * N_ + j0 + lm];
        const unsigned long long bal = __ballot(av != 0.0f);
        if (lane == 0)  madj[wid * 4 + 2 * p]     = (unsigned)bal;
        if (lane == 32) madj[wid * 4 + 2 * p + 1] = (unsigned)(bal >> 32);
    }
    // B fragments for this wave's two mt tiles
    short8_t Bf0, Bf1;
    #pragma unroll
    for (int jj = 0; jj < 8; ++jj) {
        Bf0[jj] = f2bf(We[(8 * g + jj) * MID_ + mtg * 64 + lm]);
        Bf1[jj] = f2bf(We[(8 * g + jj) * MID_ + mtg * 64 + 32 + lm]);
    }
    const float b2v0 = b2[mtg * 64 + lm];
    const float b2v1 = b2[mtg * 64 + 32 + lm];

    f32x16 accm0, accm1;
    #pragma unroll
    for (int r = 0; r < 16; ++r) { accm0[r] = -INFINITY; accm1[r] = -INFINITY; }

    __syncthreads();

    if (t < 32) {   // all-ones column -> -inf floor, else 0 (read in epilogue)
        unsigned ao = 0xFFFFFFFFu;
        #pragma unroll
        for (int i2 = 0; i2 < 32; ++i2) ao &= madj[i2];
        anyzf[t] = ((ao >> t) & 1u) ? -INFINITY : 0.0f;
    }

    // ---- main loop: this wave's 8 i's, two mt tiles each ----
    const float* efr = ef + (((size_t)(b * N_ + i0 + ig * 8)) * N_ + j0 + lm) * FE + 8 * g;
    #pragma unroll 2
    for (int ii = 0; ii < 8; ++ii) {
        const int i_l = ig * 8 + ii;
        const float4 ea = *(const float4*)efr;
        const float4 eb = *(const float4*)(efr + 4);
        efr += (size_t)N_ * FE;
        short8_t Af;
        Af[0] = f2bf(ea.x); Af[1] = f2bf(ea.y); Af[2] = f2bf(ea.z); Af[3] = f2bf(ea.w);
        Af[4] = f2bf(eb.x); Af[5] = f2bf(eb.y); Af[6] = f2bf(eb.z); Af[7] = f2bf(eb.w);

        const unsigned vmg = madj[i_l] >> (4 * g);
        const float m2v0 = m2l[i_l * MID_ + mtg * 64 + lm]      + b2v0;
        const float m2v1 = m2l[i_l * MID_ + mtg * 64 + 32 + lm] + b2v1;
        // shared mask, built once per i
        f32x16 msk;
        #pragma unroll
        for (int r = 0; r < 16; ++r) {
            const int cr = (r & 3) + 8 * (r >> 2);
            msk[r] = (vmg & (1u << cr)) ? 0.0f : -INFINITY;
        }
        f32x16 C0;
        #pragma unroll
        for (int r = 0; r < 16; ++r) C0[r] = m2v0 + msk[r];
        const f32x16 S0 = __builtin_amdgcn_mfma_f32_32x32x16_bf16(Af, Bf0, C0, 0, 0, 0);
        #pragma unroll
        for (int r = 0; r < 16; ++r) accm0[r] = fmaxf(accm0[r], S0[r]);

        f32x16 C1;
        #pragma unroll
        for (int r = 0; r < 16; ++r) C1[r] = m2v1 + msk[r];
        const f32x16 S1 = __builtin_amdgcn_mfma_f32_32x32x16_bf16(Af, Bf1, C1, 0, 0, 0);
        #pragma unroll
        for (int r = 0; r < 16; ++r) accm1[r] = fmaxf(accm1[r], S1[r]);
    }

    // ---- pairwise merge across ig (per mtg), no atomics ----
    __syncthreads();                        // all loops done (T safe to write)
    if (ig & 1) {                           // ig 1,3 -> T[mtg][ig>>1]
        float* Tw = T[mtg][ig >> 1];
        #pragma unroll
        for (int r = 0; r < 16; ++r) {
            const int jrow = (r & 3) + 8 * (r >> 2) + 4 * g;
            Tw[jrow * 64 + lm]      = accm0[r];
            Tw[jrow * 64 + 32 + lm] = accm1[r];
        }
    }
    __syncthreads();
    if (!(ig & 1)) {                        // ig 0,2: fold partner in
        const float* Tr = T[mtg][ig >> 1];
        #pragma unroll
        for (int r = 0; r < 16; ++r) {
            const int jrow = (r & 3) + 8 * (r >> 2) + 4 * g;
            accm0[r] = fmaxf(accm0[r], Tr[jrow * 64 + lm]);
            accm1[r] = fmaxf(accm1[r], Tr[jrow * 64 + 32 + lm]);
        }
    }
    if (ig == 2) {                          // publish merged upper half
        float* Tw = T[mtg][1];
        #pragma unroll
        for (int r = 0; r < 16; ++r) {
            const int jrow = (r & 3) + 8 * (r >> 2) + 4 * g;
            Tw[jrow * 64 + lm]      = accm0[r];
            Tw[jrow * 64 + 32 + lm] = accm1[r];
        }
    }
    __syncthreads();
    float* ftile = m2l;                     // m2l reads all done
    if (ig == 0) {                          // final fold + write ftile
        const float* Tr = T[mtg][1];
        #pragma unroll
        for (int r = 0; r < 16; ++r) {
            const int jrow = (r & 3) + 8 * (r >> 2) + 4 * g;
            const float v0 = fmaxf(accm0[r], Tr[jrow * 64 + lm]);
            const float v1 = fmaxf(accm1[r], Tr[jrow * 64 + 32 + lm]);
            ftile[jrow * MID_ + mtg * 64 + lm]      = v0;
            ftile[jrow * MID_ + mtg * 64 + 32 + lm] = v1;
        }
    }
    __syncthreads();

    // epilogue: + (msg1c_raw + msgg), 0-floor, coalesced f32 store (r10)
    {
        const int jrow = t >> 4, m0 = (t & 15) * 8;
        const float az = anyzf[jrow];
        const float*  c1  = msg1c + (size_t)(b * N_ + j0 + jrow) * MID_ + m0;
        const float*  gg  = msgg + b * MID_ + m0;
        float*        dst = part  + ((size_t)(ic * 2 + b) * N_ + j0 + jrow) * MID_ + m0;
        const float*  tl  = &ftile[jrow * MID_ + m0];
        const float4 c1a = *(const float4*)c1;
        const float4 c1b = *(const float4*)(c1 + 4);
        const float4 g1a = *(const float4*)gg;
        const float4 g1b = *(const float4*)(gg + 4);
        float4 o0, o1;
        o0.x = fmaxf(tl[0] + c1a.x + g1a.x, az);
        o0.y = fmaxf(tl[1] + c1a.y + g1a.y, az);
        o0.z = fmaxf(tl[2] + c1a.z + g1a.z, az);
        o0.w = fmaxf(tl[3] + c1a.w + g1a.w, az);
        o1.x = fmaxf(tl[4] + c1b.x + g1b.x, az);
        o1.y = fmaxf(tl[5] + c1b.y + g1b.y, az);
        o1.z = fmaxf(tl[6] + c1b.z + g1b.z, az);
        o1.w = fmaxf(tl[7] + c1b.w + g1b.w, az);
        *(float4*)dst       = o0;
        *(float4*)(dst + 4) = o1;
    }
}

// ---------------------------------------------------------------------------
// kC: msgs = max over 16 f32 partials; out = (h1_raw + bo1) + msgs@Wo2 + bo2
// grid 512 = 2b x 256jt (2 rows); block 256 (byte-identical to round 10)
// ---------------------------------------------------------------------------
__global__ __launch_bounds__(256, 2) void kC(
    const float* __restrict__ part, const float* __restrict__ h1,
    const float* __restrict__ Wo2, const float* __restrict__ bo1,
    const float* __restrict__ bo2,
    float* __restrict__ out)
{
    __shared__ float ms[2 * MID_];
    const int bid = blockIdx.x;          // 512 = 2b * 256 tiles
    const int b   = bid >> 8;
    const int j0  = (bid & 255) * 2;
    const int t   = threadIdx.x;
    const int r   = t >> 7, m = t & 127;
    const size_t base = ((size_t)b * N_ + j0 + r) * MID_ + m;

    float u = -INFINITY;
    #pragma unroll
    for (int icc = 0; icc < 16; ++icc)
        u = fmaxf(u, part[(size_t)icc * 2 * N_ * MID_ + base]);
    ms[r * MID_ + m] = u;
    __syncthreads();

    float acc = h1[base] + bo1[m] + bo2[m];
    for (int k0 = 0; k0 < MID_; k0 += 8) {
        float wv[8];
        #pragma unroll
        for (int uu = 0; uu < 8; ++uu) wv[uu] = Wo2[(k0 + uu) * MID_ + m];
        #pragma unroll
        for (int uu = 0; uu < 8; ++uu) acc += ms[r * MID_ + k0 + uu] * wv[uu];
    }
    out[base] = acc;
}

// ---------------------------------------------------------------------------
extern "C" void kernel_launch(void* const* d_in, const int* in_sizes, int n_in,
                              void* d_out, int out_size, void* d_ws, size_t ws_size,
                              hipStream_t stream)
{
    const float* feat = (const float*)d_in[0];
    const float* ef   = (const float*)d_in[1];
    const float* gf   = (const float*)d_in[2];
    const float* adj  = (const float*)d_in[3];
    const float* W1   = (const float*)d_in[4];
    const float* b1   = (const float*)d_in[5];
    const float* W2   = (const float*)d_in[6];
    const float* b2   = (const float*)d_in[7];
    const float* We   = (const float*)d_in[8];
    const float* be   = (const float*)d_in[9];
    const float* Wg   = (const float*)d_in[10];
    const float* bg   = (const float*)d_in[11];
    const float* Wo1  = (const float*)d_in[12];
    const float* bo1  = (const float*)d_in[13];
    const float* Wo2  = (const float*)d_in[14];
    const float* bo2  = (const float*)d_in[15];
    float* out = (float*)d_out;

    float* ws    = (float*)d_ws;
    float* msg1c = ws;                        // 131072 f32 (raw feat@W1)
    float* msg2  = ws + 131072;               // 131072 f32 (raw feat@W2)
    float* h1    = ws + 262144;               // 131072 f32 (raw feat@Wo1)
    float* part  = ws + 393216;               // 16ic*2b*512*128 f32 = 8 MB
    float* msgg  = ws + 393216 + 2097152;     // 256 f32

    hipLaunchKernelGGL(kA, dim3(386), dim3(64), 0, stream,
        feat, gf, W1, b1, W2, be, Wg, bg, Wo1, msg1c, msg2, h1, msgg);
    hipLaunchKernelGGL(kB, dim3(512), dim3(512), 0, stream,
        ef, adj, We, b2, msg1c, msg2, msgg, part);
    hipLaunchKernelGGL(kC, dim3(512), dim3(256), 0, stream,
        part, h1, Wo2, bo1, bo2, out);
}